// Round 2
// baseline (34.477 us; speedup 1.0000x reference)
//
#include <hip/hip_runtime.h>
#include <cmath>

// RMSDLoss (batched Kabsch RMSD, mean over batch), two-kernel split:
//   1) stats_kernel: pure streaming — per-row 17 sufficient statistics
//      (Σp, Σq, Σ|p|², Σ|q|², Σ p_i q_j) -> d_ws as [17][B] (SoA).
//      No fp64, minimal VGPR -> full occupancy for the memory-bound phase.
//   2) solve_kernel: one block; 2048 fp32 3x3 eigen-solves (8/thread, all
//      lanes busy) -> rms per row -> block-reduced mean -> d_out[0].

constexpr int BLOCK = 256;
constexpr int NWAVE = BLOCK / 64;
constexpr int NS = 17;

__global__ __launch_bounds__(BLOCK) void stats_kernel(
    const float* __restrict__ yp,   // [B,N,3] coords (y_prime)
    const float* __restrict__ yr,   // [B,N,3] reference (y)
    float* __restrict__ stats,      // [NS][B]
    int n, int B)
{
    const int b   = blockIdx.x;
    const int tid = threadIdx.x;
    const size_t row = (size_t)b * (size_t)n * 3u;
    const float4* p4 = (const float4*)(yp + row);
    const float4* r4 = (const float4*)(yr + row);

    float s1x=0.f,s1y=0.f,s1z=0.f, s2x=0.f,s2y=0.f,s2z=0.f, sq1=0.f,sq2=0.f;
    float c00=0.f,c01=0.f,c02=0.f,c10=0.f,c11=0.f,c12=0.f,c20=0.f,c21=0.f,c22=0.f;

    const int ngroups = n >> 2;   // 4 atoms = 12 floats = 3 float4 per group
    for (int g = tid; g < ngroups; g += BLOCK) {
        float4 a0 = p4[g*3+0], a1 = p4[g*3+1], a2 = p4[g*3+2];
        float4 b0 = r4[g*3+0], b1 = r4[g*3+1], b2 = r4[g*3+2];
        float px[4]={a0.x,a0.w,a1.z,a2.y};
        float py[4]={a0.y,a1.x,a1.w,a2.z};
        float pz[4]={a0.z,a1.y,a2.x,a2.w};
        float qx[4]={b0.x,b0.w,b1.z,b2.y};
        float qy[4]={b0.y,b1.x,b1.w,b2.z};
        float qz[4]={b0.z,b1.y,b2.x,b2.w};
        #pragma unroll
        for (int k=0;k<4;k++){
            s1x+=px[k]; s1y+=py[k]; s1z+=pz[k];
            s2x+=qx[k]; s2y+=qy[k]; s2z+=qz[k];
            sq1 = fmaf(px[k],px[k], fmaf(py[k],py[k], fmaf(pz[k],pz[k], sq1)));
            sq2 = fmaf(qx[k],qx[k], fmaf(qy[k],qy[k], fmaf(qz[k],qz[k], sq2)));
            c00=fmaf(px[k],qx[k],c00); c01=fmaf(px[k],qy[k],c01); c02=fmaf(px[k],qz[k],c02);
            c10=fmaf(py[k],qx[k],c10); c11=fmaf(py[k],qy[k],c11); c12=fmaf(py[k],qz[k],c12);
            c20=fmaf(pz[k],qx[k],c20); c21=fmaf(pz[k],qy[k],c21); c22=fmaf(pz[k],qz[k],c22);
        }
    }

    float vals[NS] = {s1x,s1y,s1z,s2x,s2y,s2z,sq1,sq2,
                      c00,c01,c02,c10,c11,c12,c20,c21,c22};
    __shared__ float sred[NWAVE][NS];
    const int wave = tid >> 6, lane = tid & 63;
    #pragma unroll
    for (int i=0;i<NS;i++){
        float v = vals[i];
        #pragma unroll
        for (int off=32; off>0; off>>=1) v += __shfl_down(v, off, 64);
        if (lane==0) sred[wave][i] = v;
    }
    __syncthreads();

    if (tid < NS) {
        float s = 0.f;
        #pragma unroll
        for (int w=0;w<NWAVE;w++) s += sred[w][tid];
        stats[tid * B + b] = s;
    }
}

__global__ __launch_bounds__(BLOCK) void solve_kernel(
    const float* __restrict__ stats,   // [NS][B]
    float* __restrict__ out, int n, int B)
{
    const int tid = threadIdx.x;
    const float fn = (float)n;
    float acc = 0.f;

    for (int b = tid; b < B; b += BLOCK) {
        float t[NS];
        #pragma unroll
        for (int i=0;i<NS;i++) t[i] = stats[i*B + b];

        const float m1x=t[0]/fn, m1y=t[1]/fn, m1z=t[2]/fn;
        const float m2x=t[3]/fn, m2y=t[4]/fn, m2z=t[5]/fn;
        const float E0 = (t[6] - fn*(m1x*m1x+m1y*m1y+m1z*m1z))
                       + (t[7] - fn*(m2x*m2x+m2y*m2y+m2z*m2z));
        const float A00=t[8] -fn*m1x*m2x, A01=t[9] -fn*m1x*m2y, A02=t[10]-fn*m1x*m2z;
        const float A10=t[11]-fn*m1y*m2x, A11=t[12]-fn*m1y*m2y, A12=t[13]-fn*m1y*m2z;
        const float A20=t[14]-fn*m1z*m2x, A21=t[15]-fn*m1z*m2y, A22=t[16]-fn*m1z*m2z;

        const float det = A00*(A11*A22-A12*A21)
                        - A01*(A10*A22-A12*A20)
                        + A02*(A10*A21-A11*A20);

        // G = A^T A (symmetric PSD); analytic eigenvalues (fp32)
        const float G00 = A00*A00+A10*A10+A20*A20;
        const float G01 = A00*A01+A10*A11+A20*A21;
        const float G02 = A00*A02+A10*A12+A20*A22;
        const float G11 = A01*A01+A11*A11+A21*A21;
        const float G12 = A01*A02+A11*A12+A21*A22;
        const float G22 = A02*A02+A12*A12+A22*A22;

        const float q  = (G00+G11+G22)*(1.f/3.f);
        const float p1 = G01*G01 + G02*G02 + G12*G12;
        const float p2 = (G00-q)*(G00-q)+(G11-q)*(G11-q)+(G22-q)*(G22-q) + 2.f*p1;
        const float p  = sqrtf(p2*(1.f/6.f));
        float e1, e2, e3;
        if (p < 1e-20f) {
            e1 = e2 = e3 = q;
        } else {
            const float ip = 1.f/p;
            const float C00=(G00-q)*ip, C01=G01*ip, C02=G02*ip;
            const float C11=(G11-q)*ip, C12=G12*ip, C22=(G22-q)*ip;
            float detC = C00*(C11*C22-C12*C12)
                       - C01*(C01*C22-C12*C02)
                       + C02*(C01*C12-C11*C02);
            float rr = fminf(1.f, fmaxf(-1.f, 0.5f*detC));
            const float phi = acosf(rr)*(1.f/3.f);
            e1 = q + 2.f*p*cosf(phi);
            e3 = q + 2.f*p*cosf(phi + 2.0943951023931953f);  // +2*pi/3
            e2 = 3.f*q - e1 - e3;
        }
        const float s0 = sqrtf(fmaxf(e1,0.f));
        const float s1 = sqrtf(fmaxf(e2,0.f));
        const float s2 = sqrtf(fmaxf(e3,0.f));
        const float trs = s0 + s1 + ((det >= 0.f) ? s2 : -s2);
        const float msd = fmaxf(0.f, (E0 - 2.f*trs)/fn);
        acc += sqrtf(msd);
    }

    #pragma unroll
    for (int off=32; off>0; off>>=1) acc += __shfl_down(acc, off, 64);
    __shared__ float sred[NWAVE];
    const int wave = tid >> 6, lane = tid & 63;
    if (lane==0) sred[wave] = acc;
    __syncthreads();
    if (tid == 0) {
        float tot = 0.f;
        #pragma unroll
        for (int w=0; w<NWAVE; w++) tot += sred[w];
        out[0] = tot / (float)B;
    }
}

extern "C" void kernel_launch(void* const* d_in, const int* in_sizes, int n_in,
                              void* d_out, int out_size, void* d_ws, size_t ws_size,
                              hipStream_t stream) {
    const float* yp = (const float*)d_in[0];   // y_prime [B,N,3] f32
    const float* yr = (const float*)d_in[1];   // y       [B,N,3] f32
    const int N = 2048;
    const int B = in_sizes[0] / (N * 3);
    float* stats_ws = (float*)d_ws;            // NS*B floats of scratch

    stats_kernel<<<B, BLOCK, 0, stream>>>(yp, yr, stats_ws, N, B);
    solve_kernel<<<1, BLOCK, 0, stream>>>(stats_ws, (float*)d_out, N, B);
}